// Round 1
// baseline (409.658 us; speedup 1.0000x reference)
//
#include <hip/hip_runtime.h>
#include <hip/hip_bf16.h>
#include <cstdint>

#define N_FEATS_IN 256
#define HID 128
#define OUTF 64
#define NBMAX 400   // max buckets (N<=102400); N=100000 -> NB=391
#define BCAP 6144   // max edges staged in LDS per bucket (mean 4096, 30 sigma margin)
#define XS_STRIDE 264

typedef __bf16 bf16x8 __attribute__((ext_vector_type(8)));
typedef __bf16 bf16x4 __attribute__((ext_vector_type(4)));
typedef __bf16 bf16x2 __attribute__((ext_vector_type(2)));
typedef float f32x4 __attribute__((ext_vector_type(4)));

// ---- CSR build: LDS counting-sort by 256-node bucket --------------------
// Avoids per-edge global atomics entirely (gfx950 global atomic RMW writes
// through to HBM ~32B each — measured 56 MB WRITE for 1.6M atomics).

// K1: per-block LDS histogram over buckets; one global atomic per
// (block,bucket) reserves that block's range within the bucket.
__global__ __launch_bounds__(256) void bucket_count(const int* __restrict__ ei, int E,
    int CH, int NB, int* __restrict__ gbk, int* __restrict__ bbase) {
  __shared__ int cnt[NBMAX];
  const int t = threadIdx.x, blk = blockIdx.x;
  for (int i = t; i < NB; i += 256) cnt[i] = 0;
  __syncthreads();
  int base = blk * CH, lim = min(base + CH, E);
  for (int i = base + t; i < lim; i += 256) atomicAdd(&cnt[ei[E + i] >> 8], 1);
  __syncthreads();
  for (int i = t; i < NB; i += 256) {
    int b = (i + blk) % NB;  // stagger to spread atomic line contention
    int v = cnt[b];
    bbase[(size_t)blk * NB + b] = (v > 0) ? atomicAdd(&gbk[b], v) : 0;
  }
}

// K2: exclusive scan of NB bucket totals (NB <= 512)
__global__ __launch_bounds__(512) void bucket_scan(const int* __restrict__ gbk,
    int* __restrict__ gbkoff, int NB, int E) {
  __shared__ int ts[512];
  const int t = threadIdx.x;
  int v = (t < NB) ? gbk[t] : 0;
  ts[t] = v;
  __syncthreads();
  for (int off = 1; off < 512; off <<= 1) {
    int u = (t >= off) ? ts[t - off] : 0;
    __syncthreads();
    ts[t] += u;
    __syncthreads();
  }
  if (t < NB) gbkoff[t] = ts[t] - v;
  if (t == 0) gbkoff[NB] = E;
}

// K3: scatter edges into bucket-grouped array via LDS cursors (runs ~128B)
__global__ __launch_bounds__(256) void bucket_scatter(const int* __restrict__ ei, int E,
    int CH, int NB, const int* __restrict__ gbkoff, const int* __restrict__ bbase,
    int2* __restrict__ bucketed) {
  __shared__ int cur[NBMAX];
  const int t = threadIdx.x, blk = blockIdx.x;
  for (int i = t; i < NB; i += 256)
    cur[i] = gbkoff[i] + bbase[(size_t)blk * NB + i];
  __syncthreads();
  int base = blk * CH, lim = min(base + CH, E);
  for (int i = base + t; i < lim; i += 256) {
    int s = ei[i];
    int c = ei[E + i];
    int p = atomicAdd(&cur[c >> 8], 1);
    bucketed[p] = make_int2(s, c);
  }
}

// K4: per-bucket local CSR: LDS histogram (256 nodes) + LDS scan -> ptr,
// dinv, and in-bucket ordered csrc. ptr needs no global node scan:
// ptr[node] = gbkoff[bucket] + local_exclusive[node&255].
__global__ __launch_bounds__(256) void bucket_csr(const int2* __restrict__ bucketed,
    const int* __restrict__ gbkoff, int NB, int N, int E,
    float* __restrict__ dinv, int* __restrict__ ptr, int* __restrict__ csrc) {
  __shared__ int2 eb[BCAP];
  __shared__ int cnt[256], scn[256], cur[256];
  const int b = blockIdx.x, t = threadIdx.x;
  const int beg = gbkoff[b], end = gbkoff[b + 1];
  const int M = end - beg;
  cnt[t] = 0;
  __syncthreads();
  const bool inlds = (M <= BCAP);
  if (inlds) {
    for (int i = t; i < M; i += 256) {
      int2 r = bucketed[beg + i];
      eb[i] = r;
      atomicAdd(&cnt[r.y & 255], 1);
    }
  } else {
    for (int i = t; i < M; i += 256) atomicAdd(&cnt[bucketed[beg + i].y & 255], 1);
  }
  __syncthreads();
  const int c0 = cnt[t];
  scn[t] = c0;
  __syncthreads();
  for (int off = 1; off < 256; off <<= 1) {
    int u = (t >= off) ? scn[t - off] : 0;
    __syncthreads();
    scn[t] += u;
    __syncthreads();
  }
  const int excl = scn[t] - c0;
  const int node = b * 256 + t;
  if (node < N) {
    ptr[node] = beg + excl;
    dinv[node] = rsqrtf((float)(c0 + 1));  // +1 self-loop
  }
  if (b == NB - 1 && t == 0) ptr[N] = E;
  cur[t] = excl;
  __syncthreads();
  if (inlds) {
    for (int i = t; i < M; i += 256) {
      int2 r = eb[i];
      int slot = atomicAdd(&cur[r.y & 255], 1);
      csrc[beg + slot] = r.x;
    }
  } else {
    for (int i = t; i < M; i += 256) {
      int2 r = bucketed[beg + i];
      int slot = atomicAdd(&cur[r.y & 255], 1);
      csrc[beg + slot] = r.x;
    }
  }
}

// ---- weight repack into MFMA B-fragment order ---------------------------

__global__ __launch_bounds__(256) void pack_all_kernel(const float* __restrict__ W1,
    const float* __restrict__ Wmu, const float* __restrict__ Wlv,
    __bf16* __restrict__ W1p, __bf16* __restrict__ Wcp) {
  int idx = blockIdx.x * 256 + threadIdx.x;  // 32768 + 16384 = 49152
  if (idx < 32768) {
    int j = idx & 7, l = (idx >> 3) & 63, t = (idx >> 9) & 7, s = idx >> 12;
    int k = s * 32 + (l >> 4) * 8 + j;
    int n = t * 16 + (l & 15);
    W1p[idx] = (__bf16)W1[k * HID + n];
  } else if (idx < 49152) {
    int i2 = idx - 32768;
    int j = i2 & 7, l = (i2 >> 3) & 63, t = (i2 >> 9) & 7, s = i2 >> 12;
    int k = s * 32 + (l >> 4) * 8 + j;
    int g = t * 16 + (l & 15);
    float v = (g < OUTF) ? Wmu[k * OUTF + g] : Wlv[k * OUTF + (g - OUTF)];
    Wcp[i2] = (__bf16)v;
  }
}

// ---- GEMM1 (MFMA): Yb[N][128] = bf16( dinv[row] * (X[N][256] @ W1) ) ----
// dinv is folded into the stored features so the aggregation kernels never
// have to gather dinv[src] per edge (pure row-sum instead).

__global__ __launch_bounds__(256) void gemm1_mfma(const float* __restrict__ X,
    const __bf16* __restrict__ Wp, const float* __restrict__ dinv,
    __bf16* __restrict__ Yb, int nrows) {
  __shared__ __bf16 xs[128 * XS_STRIDE];  // 66 KB
  const int tid = threadIdx.x;
  const int rowbase = blockIdx.x * 128;

#pragma unroll
  for (int i = 0; i < 32; ++i) {
    int idx = i * 256 + tid;
    int row = idx >> 6;
    int cc = idx & 63;
    int gr = min(rowbase + row, nrows - 1);
    float4 v = ((const float4*)(X + (size_t)gr * N_FEATS_IN))[cc];
    bf16x4 b;
    b[0] = (__bf16)v.x; b[1] = (__bf16)v.y; b[2] = (__bf16)v.z; b[3] = (__bf16)v.w;
    *(bf16x4*)(xs + row * XS_STRIDE + cc * 4) = b;
  }
  __syncthreads();

  const int lane = tid & 63;
  const int wave = tid >> 6;
  const int lm = lane & 15;
  const int q = lane >> 4;
  const bf16x8* wp = (const bf16x8*)Wp;

  f32x4 acc[2][8];
#pragma unroll
  for (int m = 0; m < 2; ++m)
#pragma unroll
    for (int t = 0; t < 8; ++t) acc[m][t] = (f32x4)0.f;

#pragma unroll
  for (int s = 0; s < 8; ++s) {
    bf16x8 a0 = *(const bf16x8*)(xs + (wave * 32 + lm) * XS_STRIDE + s * 32 + q * 8);
    bf16x8 a1 = *(const bf16x8*)(xs + (wave * 32 + 16 + lm) * XS_STRIDE + s * 32 + q * 8);
#pragma unroll
    for (int t = 0; t < 8; ++t) {
      bf16x8 b = wp[(s * 8 + t) * 64 + lane];
      acc[0][t] = __builtin_amdgcn_mfma_f32_16x16x32_bf16(a0, b, acc[0][t], 0, 0, 0);
      acc[1][t] = __builtin_amdgcn_mfma_f32_16x16x32_bf16(a1, b, acc[1][t], 0, 0, 0);
    }
  }

  // per-thread row scales (8 broadcast loads, L2-hot)
  float dd[2][4];
#pragma unroll
  for (int m = 0; m < 2; ++m)
#pragma unroll
    for (int r2 = 0; r2 < 4; ++r2) {
      int row = rowbase + wave * 32 + m * 16 + q * 4 + r2;
      dd[m][r2] = (row < nrows) ? dinv[row] : 0.f;
    }

#pragma unroll
  for (int m = 0; m < 2; ++m) {
    int rb = rowbase + wave * 32 + m * 16 + q * 4;
#pragma unroll
    for (int t = 0; t < 8; ++t) {
#pragma unroll
      for (int r2 = 0; r2 < 4; ++r2) {
        int row = rb + r2;
        if (row < nrows)
          Yb[(size_t)row * HID + t * 16 + lm] = (__bf16)(acc[m][t][r2] * dd[m][r2]);
      }
    }
  }
}

// ---- aggregation (bf16 in/out, f32 accumulate) --------------------------
// Inputs are pre-scaled by dinv (F'[r] = dinv[r]*F[r]), so per target c:
//   sum = F'[c] + sum_{e} F'[src_e]          (self-loop = init term)
//   relu variant (layer 1): out = dinv[c] * relu(dinv[c]*sum + b)   [stores H']
//   plain variant (layer 2): out = dinv[c] * sum                    [stores G]
// Structure for memory-level parallelism: 256-thread blocks (4 waves,
// 8 blocks/CU -> 32 waves/CU), 2 nodes per wave (32 lanes x bf16x4 each)
// -> 2 independent gather chains per wave, and no per-edge dinv load.

__global__ __launch_bounds__(256) void agg_kernel(const __bf16* __restrict__ Fin,
    const int* __restrict__ ptr, const int* __restrict__ csrc,
    const float* __restrict__ dinv, const float* __restrict__ bias,
    __bf16* __restrict__ Fout, int do_relu, int N) {
  const int tid = threadIdx.x;
  const int lane = tid & 63;
  const int half = lane >> 5;   // which of the wave's 2 nodes
  const int l = lane & 31;      // feature group: feats 4l..4l+3
  const int c = blockIdx.x * 8 + (tid >> 6) * 2 + half;
  if (c >= N) return;

  const float d = dinv[c];
  bf16x4 sv = ((const bf16x4*)(Fin + (size_t)c * HID))[l];  // self term F'[c]
  float a0 = (float)sv[0], a1 = (float)sv[1], a2 = (float)sv[2], a3 = (float)sv[3];

  const int beg = ptr[c], end = ptr[c + 1];
  int e = beg;
  for (; e + 8 <= end; e += 8) {
    int r[8];
#pragma unroll
    for (int i = 0; i < 8; ++i) r[i] = csrc[e + i];
    bf16x4 v[8];
#pragma unroll
    for (int i = 0; i < 8; ++i) v[i] = ((const bf16x4*)(Fin + (size_t)r[i] * HID))[l];
#pragma unroll
    for (int i = 0; i < 8; ++i) {
      a0 += (float)v[i][0];
      a1 += (float)v[i][1];
      a2 += (float)v[i][2];
      a3 += (float)v[i][3];
    }
  }
  for (; e < end; ++e) {
    int r = csrc[e];
    bf16x4 v = ((const bf16x4*)(Fin + (size_t)r * HID))[l];
    a0 += (float)v[0];
    a1 += (float)v[1];
    a2 += (float)v[2];
    a3 += (float)v[3];
  }

  if (do_relu) {
    float4 bv = ((const float4*)bias)[l];
    a0 = fmaxf(fmaf(d, a0, bv.x), 0.f) * d;
    a1 = fmaxf(fmaf(d, a1, bv.y), 0.f) * d;
    a2 = fmaxf(fmaf(d, a2, bv.z), 0.f) * d;
    a3 = fmaxf(fmaf(d, a3, bv.w), 0.f) * d;
  } else {
    a0 *= d; a1 *= d; a2 *= d; a3 *= d;
  }
  bf16x4 o;
  o[0] = (__bf16)a0; o[1] = (__bf16)a1; o[2] = (__bf16)a2; o[3] = (__bf16)a3;
  ((bf16x4*)(Fout + (size_t)c * HID))[l] = o;
}

// ---- GEMM2 (MFMA): [mu|lv] = Gb[N][128] @ Wc[128][128] + bias -----------

__global__ __launch_bounds__(256) void gemm2_mfma(const __bf16* __restrict__ Gb,
    const __bf16* __restrict__ Wp, const float* __restrict__ bmu,
    const float* __restrict__ blv, float* __restrict__ out, int nrows, int ntiles) {
  __shared__ __bf16 bs[16384];  // 32 KB: full Wc in B-frag order
  const int tid = threadIdx.x;
  {
    const float4* s4 = (const float4*)Wp;
    float4* d4 = (float4*)bs;
#pragma unroll
    for (int i = 0; i < 8; ++i) d4[tid + 256 * i] = s4[tid + 256 * i];
  }
  __syncthreads();
  const int lane = tid & 63;
  const int wave = tid >> 6;
  const int lm = lane & 15;
  const int q = lane >> 4;
  const bf16x8* bsv = (const bf16x8*)bs;

  float bv[8];
  size_t obase[8];
#pragma unroll
  for (int t = 0; t < 8; ++t) {
    int col = t * 16 + lm;
    bv[t] = (col < OUTF) ? bmu[col] : blv[col - OUTF];
    obase[t] = (col < OUTF) ? (size_t)col : ((size_t)nrows * OUTF + (col - OUTF));
  }

  for (int tile = blockIdx.x; tile < ntiles; tile += gridDim.x) {
    const int row0 = tile * 64 + wave * 16;
    const int r = min(row0 + lm, nrows - 1);
    const bf16x8* gp = (const bf16x8*)(Gb + (size_t)r * HID);

    bf16x8 xa[4];
#pragma unroll
    for (int s = 0; s < 4; ++s) xa[s] = gp[s * 4 + q];

    f32x4 acc[8];
#pragma unroll
    for (int t = 0; t < 8; ++t) acc[t] = (f32x4)0.f;

#pragma unroll
    for (int s = 0; s < 4; ++s) {
#pragma unroll
      for (int t = 0; t < 8; ++t)
        acc[t] = __builtin_amdgcn_mfma_f32_16x16x32_bf16(xa[s], bsv[(s * 8 + t) * 64 + lane],
                                                         acc[t], 0, 0, 0);
    }
#pragma unroll
    for (int t = 0; t < 8; ++t) {
#pragma unroll
      for (int r2 = 0; r2 < 4; ++r2) {
        int row = row0 + q * 4 + r2;
        if (row < nrows) out[obase[t] + (size_t)row * OUTF] = acc[t][r2] + bv[t];
      }
    }
  }
}

// ---- launch -------------------------------------------------------------

extern "C" void kernel_launch(void* const* d_in, const int* in_sizes, int n_in,
                              void* d_out, int out_size, void* d_ws, size_t ws_size,
                              hipStream_t stream) {
  const float* X   = (const float*)d_in[0];
  const int*   ei  = (const int*)d_in[1];
  const float* W1  = (const float*)d_in[2];
  const float* b1  = (const float*)d_in[3];
  const float* Wmu = (const float*)d_in[4];
  const float* bmu = (const float*)d_in[5];
  const float* Wlv = (const float*)d_in[6];
  const float* blv = (const float*)d_in[7];
  float* out = (float*)d_out;

  const int N = in_sizes[0] / N_FEATS_IN;   // 100000
  const int E = in_sizes[1] / 2;            // 1600000

  char* ws = (char*)d_ws;
  size_t off = 0;
  auto alloc = [&](size_t bytes) -> void* {
    void* p = ws + off;
    off += (bytes + 255) & ~(size_t)255;
    return p;
  };
  __bf16* Yb   = (__bf16*)alloc((size_t)N * HID * 2);  // gemm1 out; reused as G
  __bf16* Hb   = (__bf16*)alloc((size_t)N * HID * 2);  // dinv*relu(Â Y + b1)
  float* dinv  = (float*)alloc((size_t)N * 4);
  int*   ptr   = (int*)alloc((size_t)(N + 1) * 4);
  int2*  bucketed = (int2*)alloc((size_t)E * 8);
  int*   csrc  = (int*)alloc((size_t)E * 4);
  int*   gbk   = (int*)alloc((size_t)NBMAX * 4);
  int*   gbkoff = (int*)alloc((size_t)(NBMAX + 1) * 4);
  int*   bbase = (int*)alloc((size_t)256 * NBMAX * 4);
  __bf16* W1p  = (__bf16*)alloc(32768 * 2);
  __bf16* Wcp  = (__bf16*)alloc(16384 * 2);
  (void)ws_size; (void)n_in; (void)out_size;

  const int NB = (N + 255) >> 8;            // 391
  const int P = 256;
  const int CH = (E + P - 1) / P;           // 6250

  hipMemsetAsync(gbk, 0, (size_t)NB * 4, stream);
  bucket_count<<<P, 256, 0, stream>>>(ei, E, CH, NB, gbk, bbase);
  bucket_scan<<<1, 512, 0, stream>>>(gbk, gbkoff, NB, E);
  bucket_scatter<<<P, 256, 0, stream>>>(ei, E, CH, NB, gbkoff, bbase, bucketed);
  bucket_csr<<<NB, 256, 0, stream>>>(bucketed, gbkoff, NB, N, E, dinv, ptr, csrc);
  pack_all_kernel<<<192, 256, 0, stream>>>(W1, Wmu, Wlv, W1p, Wcp);

  int g1 = (N + 127) / 128;
  gemm1_mfma<<<g1, 256, 0, stream>>>(X, W1p, dinv, Yb, N);
  int ga = (N + 7) / 8;
  agg_kernel<<<ga, 256, 0, stream>>>(Yb, ptr, csrc, dinv, b1, Hb, 1, N);  // H' = dinv*relu(ÂY+b1)
  agg_kernel<<<ga, 256, 0, stream>>>(Hb, ptr, csrc, dinv, b1, Yb, 0, N);  // G = ÂH
  int ntiles2 = (N + 63) / 64;
  int g2 = ntiles2 < 768 ? ntiles2 : 768;
  gemm2_mfma<<<g2, 256, 0, stream>>>(Yb, Wcp, bmu, blv, out, N, ntiles2);
}